// Round 17
// baseline (112.509 us; speedup 1.0000x reference)
//
#include <hip/hip_runtime.h>
#include <hip/hip_bf16.h>

#define T 50
#define NB 64
#define NS 512
#define START_TAG 48
#define STOP_TAG 49

typedef _Float16 f16_t;
typedef _Float16 f16x2 __attribute__((ext_vector_type(2)));
typedef _Float16 f16x4 __attribute__((ext_vector_type(4)));
typedef _Float16 f16x8 __attribute__((ext_vector_type(8)));
typedef float    f32x4 __attribute__((ext_vector_type(4)));

static constexpr float LOG2E = 1.4426950408889634f;
static constexpr float LN2F  = 0.6931471805599453f;
static constexpr float S_E   = 6.0f;     // static log2 shift folded out of E
#define NEG_BIG (-1.0e38f)

__device__ __forceinline__ float fexp2(float x) { return __builtin_amdgcn_exp2f(x); }
__device__ __forceinline__ float flog2(float x) { return __builtin_amdgcn_logf(x); }
__device__ __forceinline__ f16x2 bcast_h2(f16x2 v, int src) {
    unsigned u = __builtin_amdgcn_readlane(__builtin_bit_cast(unsigned, v), src);
    return __builtin_bit_cast(f16x2, u);
}
__device__ __forceinline__ f16x2 pack_h2(float a, float b) {
    return __builtin_bit_cast(f16x2, __builtin_amdgcn_cvt_pkrtz(a, b));
}

// async global->LDS, 16 B per lane (dest = wave-uniform base + lane*16,
// src is per-lane). Counted by vmcnt.
__device__ __forceinline__ void gload_lds16(const void* g, void* l) {
    __builtin_amdgcn_global_load_lds(
        (const __attribute__((address_space(1))) void*)g,
        (__attribute__((address_space(3))) void*)l, 16, 0, 0);
}

// Full-wave (64-lane) fmax via DPP (VALU pipe) -> uniform value via lane 63.
__device__ __forceinline__ float wave_fmax_dpp(float x) {
#define DPP_STEP(ctrl)                                                        \
    do {                                                                      \
        int _s = __builtin_bit_cast(int, x);                                  \
        int _p = __builtin_amdgcn_update_dpp(_s, _s, (ctrl), 0xf, 0xf, false);\
        x = fmaxf(x, __builtin_bit_cast(float, _p));                          \
    } while (0)
    DPP_STEP(0x111);  // row_shr:1
    DPP_STEP(0x112);  // row_shr:2
    DPP_STEP(0x114);  // row_shr:4
    DPP_STEP(0x118);  // row_shr:8
    DPP_STEP(0x142);  // row_bcast:15
    DPP_STEP(0x143);  // row_bcast:31
#undef DPP_STEP
    return __builtin_bit_cast(float,
        __builtin_amdgcn_readlane(__builtin_bit_cast(int, x), 63));
}

// =====================================================================
// Kernel 1 (r16-verified, byte-identical): hybrid Afrag (kb 0-1 regs,
// kb 2-3 LDS), NCHT=32 grid -> 8 blocks/CU. 42.8us measured, occ 53%.
// =====================================================================
template<int NCHT, int CHLT>
__global__ __launch_bounds__(256, 8)
void crf_chunk(const float* __restrict__ feats, const int* __restrict__ mask,
               const float* __restrict__ trans, f16_t* __restrict__ wsCt,
               float* __restrict__ wsD, float* __restrict__ out, int out_size) {
    const int c    = blockIdx.x;          // chunk
    const int b    = blockIdx.y;          // batch
    const int tid  = threadIdx.x;
    const int w    = tid >> 6;            // wave = column-slice owner
    const int lane = tid & 63;
    const int l15  = lane & 15;
    const int q    = lane >> 4;

    constexpr int EF_BYTES = 2 * 2 * 64 * 16;            // kb 2,3 only: 4 KB
    constexpr int SF_BYTES = CHLT * 64 * 4;              // f32 per step/row
    constexpr int ML_BYTES = 64 * 72 * 2;                // epilogue transpose
    constexpr int SM_BYTES = (EF_BYTES + SF_BYTES) > ML_BYTES
                           ? (EF_BYTES + SF_BYTES) : ML_BYTES;
    __shared__ unsigned char smem[SM_BYTES];
    f16_t* Ef = (f16_t*)smem;                            // 16B pair slots
    float (*sF)[64] = (float (*)[64])(smem + EF_BYTES);

    const int t0  = c * CHLT + 1;
    const int nst = (NS - t0 < CHLT) ? (NS - t0) : CHLT;

    // ---- Afrag kb 0,1 in registers: A(mb,kb) elem j = E[16kb+4q+j][16mb+l15]
    f16x4 Afr[2][4];
    #pragma unroll
    for (int kb = 0; kb < 2; kb++)
        #pragma unroll
        for (int mb = 0; mb < 4; mb++) {
            f16x4 v;
            #pragma unroll
            for (int j = 0; j < 4; j++) {
                const int kk = 16 * kb + 4 * q + j;
                const int mm = 16 * mb + l15;
                float x = 0.f;
                if (kk < T && mm < T) x = fexp2(fmaf(trans[kk * T + mm], LOG2E, -S_E));
                v[j] = (f16_t)x;
            }
            Afr[kb][mb] = v;
        }

    // ---- Ef (kb 2,3): slot sidx = (kbr*2+mbp)*64+ln holds A(2mbp,kb) ||
    // A(2mbp+1,kb) for target lane ln. 256 slots, one per thread.
    {
        const int sidx = tid;
        const int kbr = sidx >> 7;          // 0,1 -> kb 2,3
        const int mbp = (sidx >> 6) & 1;
        const int ln  = sidx & 63;
        const int qq  = ln >> 4;
        const int ll  = ln & 15;
        f16_t* slot = Ef + sidx * 8;
        #pragma unroll
        for (int e = 0; e < 2; e++)
            #pragma unroll
            for (int j = 0; j < 4; j++) {
                const int kk = 16 * (kbr + 2) + 4 * qq + j;
                const int mm = 16 * (2 * mbp + e) + ll;
                float x = 0.f;
                if (kk < T && mm < T) x = fexp2(fmaf(trans[kk * T + mm], LOG2E, -S_E));
                slot[e * 4 + j] = (f16_t)x;
            }
    }

    // ---- preload sF (exp2 once); 4 waves stripe the rows
    for (int r = w; r < CHLT; r += 4) {
        int tl = t0 + r; tl = tl < NS ? tl : NS - 1;
        float fv = (lane < T && r < nst) ? feats[((size_t)b * NS + tl) * T + lane] : 0.f;
        sF[r][lane] = (lane < T && r < nst) ? fexp2(fv * LOG2E) : 0.f;
    }

    // ---- mask bitmap (one ballot; per-step test is SALU)
    unsigned long long bm;
    {
        int tl = t0 + lane; tl = tl < NS ? tl : NS - 1;
        int mv = (lane < nst) ? mask[b * NS + tl] : 0;
        bm = __ballot(mv != 0);
    }
    __syncthreads();                      // Ef + sF visible to all waves

    // ---- init wave's slice of M = I: tile rb is I-block (rb, w)
    f16x4 Bt[4];
    #pragma unroll
    for (int rb = 0; rb < 4; rb++) {
        f16x4 v;
        #pragma unroll
        for (int j = 0; j < 4; j++)
            v[j] = (f16_t)((rb == w && 4 * q + j == l15) ? 1.f : 0.f);
        Bt[rb] = v;
    }

    float D  = 0.f;
    float m1 = 1.f, m2 = 1.f;             // wave max from s-1, s-2 (delayed renorm)
    const f16x8* EfL = (const f16x8*)Ef;  // [ (kbr*2+mbp)*64 + lane ]

    for (int s = 0; s < nst; s++) {
        if ((bm >> s) & 1ull) {
            // descale from max TWO doit-steps back (exact pow2; D compensates)
            int ebits = (int)((__float_as_uint(m2) >> 23) & 255) - 127;
            ebits = ebits > 14 ? 14 : (ebits < -14 ? -14 : ebits);
            const float descale = __uint_as_float((unsigned)(127 - ebits) << 23);
            D += (float)ebits + S_E;

            // 16 MFMAs: kb 0,1 from regs; kb 2,3 streamed from LDS
            const f32x4 zz = {0.f, 0.f, 0.f, 0.f};
            f32x4 acc[4];
            #pragma unroll
            for (int mb = 0; mb < 4; mb++)
                acc[mb] = __builtin_amdgcn_mfma_f32_16x16x16f16(Afr[0][mb], Bt[0], zz, 0, 0, 0);
            #pragma unroll
            for (int mb = 0; mb < 4; mb++)
                acc[mb] = __builtin_amdgcn_mfma_f32_16x16x16f16(Afr[1][mb], Bt[1], acc[mb], 0, 0, 0);
            #pragma unroll
            for (int kbr = 0; kbr < 2; kbr++) {
                f16x8 p0 = EfL[(kbr * 2 + 0) * 64 + lane];
                f16x8 p1 = EfL[(kbr * 2 + 1) * 64 + lane];
                acc[0] = __builtin_amdgcn_mfma_f32_16x16x16f16(__builtin_shufflevector(p0, p0, 0,1,2,3), Bt[2 + kbr], acc[0], 0, 0, 0);
                acc[1] = __builtin_amdgcn_mfma_f32_16x16x16f16(__builtin_shufflevector(p0, p0, 4,5,6,7), Bt[2 + kbr], acc[1], 0, 0, 0);
                acc[2] = __builtin_amdgcn_mfma_f32_16x16x16f16(__builtin_shufflevector(p1, p1, 0,1,2,3), Bt[2 + kbr], acc[2], 0, 0, 0);
                acc[3] = __builtin_amdgcn_mfma_f32_16x16x16f16(__builtin_shufflevector(p1, p1, 4,5,6,7), Bt[2 + kbr], acc[3], 0, 0, 0);
            }

            // per-mb: load cs, fold descale (exact pow2), scale, RNE f16;
            // wm via packed f16 max on the stored words
            f16x2 wmax2 = {(f16_t)0.f, (f16_t)0.f};
            #pragma unroll
            for (int mb = 0; mb < 4; mb++) {
                f32x4 cs = *(const f32x4*)&sF[s][16 * mb + 4 * q];
                float v0 = acc[mb][0] * (cs[0] * descale);
                float v1 = acc[mb][1] * (cs[1] * descale);
                float v2 = acc[mb][2] * (cs[2] * descale);
                float v3 = acc[mb][3] * (cs[3] * descale);
                f16x4 hv;
                hv[0] = (f16_t)v0; hv[1] = (f16_t)v1;   // RNE, matches prior rounds
                hv[2] = (f16_t)v2; hv[3] = (f16_t)v3;
                Bt[mb] = hv;       // D-layout == B-layout: feeds next step directly
                f16x2 lo = __builtin_shufflevector(hv, hv, 0, 1);
                f16x2 hi = __builtin_shufflevector(hv, hv, 2, 3);
                wmax2 = __builtin_elementwise_max(wmax2,
                          __builtin_elementwise_max(lo, hi));
            }
            float wm = fmaxf((float)wmax2[0], (float)wmax2[1]);

            m2 = m1;
            m1 = wave_fmax_dpp(wm);        // consumed two steps later
        }
    }

    // ---- epilogue: Ml overlaps Ef/sF (dead now); barrier first
    __syncthreads();                      // all waves done reading Ef/sF
    {
        f16_t* Ml = (f16_t*)smem;         // [64][72]
        const int P2 = 72;
        #pragma unroll
        for (int rb = 0; rb < 4; rb++) {
            f16x4 v = Bt[rb];
            #pragma unroll
            for (int r = 0; r < 4; r++)
                Ml[(16 * rb + 4 * q + r) * P2 + 16 * w + l15] = v[r];
        }
        __syncthreads();
        // wsCt row j = M row j = column j of C (combine lane j's layout)
        const int row = tid >> 2;          // 0..63
        const int seg = tid & 3;           // 32 B segment
        const f16_t* src = &Ml[row * P2 + seg * 16];
        f16_t* dst = wsCt + ((size_t)(b * NCHT + c)) * 4096 + row * 64 + seg * 16;
        ((int4*)dst)[0] = *(const int4*)&src[0];
        ((int4*)dst)[1] = *(const int4*)&src[8];
    }
    if (lane == 0) wsD[(b * NCHT + c) * 4 + w] = D;   // per-wave (per-16-C-rows) shift

    // ---- zero `out` (replaces the hipMemsetAsync graph node)
    if (c == 0 && b == 0 && tid < out_size) out[tid] = 0.f;
}

// =====================================================================
// Kernel 2 v2 (LDS-streamed): wave 0 chains NCHT chunks; chunk data is
// streamed global->LDS via global_load_lds (7x16B segs per row cover
// T=50 cols; dest = uniform base + lane*16, src per-lane = row `lane`).
// 4-slot ring x 2 chunks/group (14 loads/group, 56 KB), issued 3 groups
// ahead; consume waits use COUNTED s_waitcnt vmcnt(42/28/14/0) +
// sched_barrier(0) (rule-18 fence) -> group g's data was issued ~3
// consume-rounds (~2000cy) earlier, exposing zero latency. Replaces the
// 2-deep register prefetch that couldn't reach cross-XCD depth (~900cy).
// Wave 1: gold score (unchanged). Dq[lane>>4] absorbs per-wave renorm.
// =====================================================================
template<int NCHT>
__global__ __launch_bounds__(128, 1)
void crf_combine(const float* __restrict__ feats, const int* __restrict__ mask,
                 const int* __restrict__ tags, const float* __restrict__ trans,
                 const f16_t* __restrict__ wsCt, const float* __restrict__ wsD,
                 float* __restrict__ out) {
    const int b    = blockIdx.x;
    const int tid  = threadIdx.x;
    const int wv   = tid >> 6;
    const int lane = tid & 63;
    constexpr int G = NCHT / 2;           // groups of 2 chunks

    __shared__ f16_t sBuf[4 * 14 * 512];  // 4 slots x 14 regions x 1KB = 56KB
    __shared__ float sGold;
    float fwd = 0.f;

    if (wv == 1) {
        float gsum = 0.f;
        int   lcnt = 0;
        for (int s = lane; s < NS; s += 64) {
            int   m  = mask[b * NS + s];
            int   tg = tags[b * NS + s];
            int   pv = (s == 0) ? START_TAG : tags[b * NS + s - 1];
            float e  = feats[((size_t)b * NS + s) * T + tg];
            float tr = trans[pv * T + tg];
            if (m) { gsum += e + tr; lcnt += 1; }
        }
        #pragma unroll
        for (int off = 32; off > 0; off >>= 1) {
            gsum += __shfl_down(gsum, off, 64);
            lcnt += __shfl_down(lcnt, off, 64);
        }
        if (lane == 0) sGold = gsum + trans[tags[b * NS + lcnt - 1] * T + STOP_TAG];
    } else {
        float part = (lane < T)
            ? (feats[(size_t)b * NS * T + lane] + trans[START_TAG * T + lane]) * LOG2E
            : NEG_BIG;

        float Dq[NCHT];
        #pragma unroll
        for (int cc = 0; cc < NCHT; cc++)
            Dq[cc] = wsD[(b * NCHT + cc) * 4 + (lane >> 4)];

        auto issueGroup = [&](int g) {
            const int slot = g & 3;
            #pragma unroll
            for (int i = 0; i < 2; i++) {
                const int cc = 2 * g + i;
                const f16_t* srcRow = wsCt + (size_t)(b * NCHT + cc) * 4096 + lane * 64;
                #pragma unroll
                for (int t = 0; t < 7; t++)
                    gload_lds16(srcRow + t * 8,
                                &sBuf[(size_t)(slot * 14 + i * 7 + t) * 512]);
            }
        };

        auto body = [&](int cc, int cur[28]) {
            float tmp = part + Dq[cc];
            float sft = wave_fmax_dpp(tmp);
            float ex  = fexp2(tmp - sft);
            float exo = __shfl_xor(ex, 1, 64);
            f16x2 pk  = pack_h2(ex, exo);

            float a0 = 0.f, a1 = 0.f, a2 = 0.f, a3 = 0.f;
            #pragma unroll
            for (int k = 0; k < 25; k += 4) {
                a0 = __builtin_amdgcn_fdot2(bcast_h2(pk, 2 * k), __builtin_bit_cast(f16x2, cur[k]), a0, false);
                if (k + 1 < 25) a1 = __builtin_amdgcn_fdot2(bcast_h2(pk, 2 * (k + 1)), __builtin_bit_cast(f16x2, cur[k + 1]), a1, false);
                if (k + 2 < 25) a2 = __builtin_amdgcn_fdot2(bcast_h2(pk, 2 * (k + 2)), __builtin_bit_cast(f16x2, cur[k + 2]), a2, false);
                if (k + 3 < 25) a3 = __builtin_amdgcn_fdot2(bcast_h2(pk, 2 * (k + 3)), __builtin_bit_cast(f16x2, cur[k + 3]), a3, false);
            }
            part = sft + flog2((a0 + a1) + (a2 + a3));
        };

        issueGroup(0);
        if (1 < G) issueGroup(1);
        if (2 < G) issueGroup(2);

        #pragma unroll
        for (int g = 0; g < G; g++) {
            if (g + 3 < G) issueGroup(g + 3);
            // counted wait: group g done <=> outstanding <= ahead*14
            const int ahead = (G - 1 - g) < 3 ? (G - 1 - g) : 3;
            if (ahead == 3)      asm volatile("s_waitcnt vmcnt(42)" ::: "memory");
            else if (ahead == 2) asm volatile("s_waitcnt vmcnt(28)" ::: "memory");
            else if (ahead == 1) asm volatile("s_waitcnt vmcnt(14)" ::: "memory");
            else                 asm volatile("s_waitcnt vmcnt(0)"  ::: "memory");
            __builtin_amdgcn_sched_barrier(0);

            #pragma unroll
            for (int i = 0; i < 2; i++) {
                const int cc = 2 * g + i;
                int cur[28];
                const int base = ((g & 3) * 14 + i * 7) * 512 + lane * 8;
                #pragma unroll
                for (int t = 0; t < 7; t++)
                    *(int4*)&cur[4 * t] = *(const int4*)&sBuf[base + t * 512];
                body(cc, cur);
            }
        }

        float v = (lane < T) ? part + trans[lane * T + STOP_TAG] * LOG2E : NEG_BIG;
        float mx = wave_fmax_dpp(v);
        float ee = (lane < T) ? fexp2(v - mx) : 0.f;
        #pragma unroll
        for (int off = 32; off > 0; off >>= 1) ee += __shfl_xor(ee, off, 64);
        fwd = (mx + flog2(ee)) * LN2F;
    }

    __syncthreads();
    if (tid == 0) atomicAdd(out, fwd - sGold);
}

extern "C" void kernel_launch(void* const* d_in, const int* in_sizes, int n_in,
                              void* d_out, int out_size, void* d_ws, size_t ws_size,
                              hipStream_t stream) {
    const float* feats = (const float*)d_in[0];
    const int*   mask  = (const int*)d_in[1];
    const int*   tags  = (const int*)d_in[2];
    const float* trans = (const float*)d_in[3];
    float* out = (float*)d_out;

    // NO hipMemsetAsync: `out` zeroed inside crf_chunk (block (0,0)).

    const size_t matBytes32 = (size_t)NB * 32 * 4096 * sizeof(f16_t);
    const size_t need32     = matBytes32 + (size_t)NB * 32 * 4 * sizeof(float);
    const size_t matBytes16 = (size_t)NB * 16 * 4096 * sizeof(f16_t);
    const size_t need16     = matBytes16 + (size_t)NB * 16 * 4 * sizeof(float);

    if (ws_size >= need32) {
        // preferred: 32 chunks x 16 steps -> 2048 blocks = 8 blocks/CU
        f16_t* wsCt = (f16_t*)d_ws;
        float* wsD  = (float*)((char*)d_ws + matBytes32);
        crf_chunk<32, 16><<<dim3(32, NB), 256, 0, stream>>>(feats, mask, trans, wsCt, wsD, out, out_size);
        crf_combine<32><<<NB, 128, 0, stream>>>(feats, mask, tags, trans, wsCt, wsD, out);
    } else if (ws_size >= need16) {
        // fallback: 16 chunks x 32 steps
        f16_t* wsCt = (f16_t*)d_ws;
        float* wsD  = (float*)((char*)d_ws + matBytes16);
        crf_chunk<16, 32><<<dim3(16, NB), 256, 0, stream>>>(feats, mask, trans, wsCt, wsD, out, out_size);
        crf_combine<16><<<NB, 128, 0, stream>>>(feats, mask, tags, trans, wsCt, wsD, out);
    } else {
        // minimal: 8 chunks x 64 steps (fits 4.2 MB)
        const size_t matBytes8 = (size_t)NB * 8 * 4096 * sizeof(f16_t);
        f16_t* wsCt = (f16_t*)d_ws;
        float* wsD  = (float*)((char*)d_ws + matBytes8);
        crf_chunk<8, 64><<<dim3(8, NB), 256, 0, stream>>>(feats, mask, trans, wsCt, wsD, out, out_size);
        crf_combine<8><<<NB, 128, 0, stream>>>(feats, mask, tags, trans, wsCt, wsD, out);
    }
}

// Round 18
// 105.190 us; speedup vs baseline: 1.0696x; 1.0696x over previous
//
#include <hip/hip_runtime.h>
#include <hip/hip_bf16.h>

#define T 50
#define NB 64
#define NS 512
#define START_TAG 48
#define STOP_TAG 49

typedef _Float16 f16_t;
typedef _Float16 f16x2 __attribute__((ext_vector_type(2)));
typedef _Float16 f16x4 __attribute__((ext_vector_type(4)));
typedef float    f32x4 __attribute__((ext_vector_type(4)));

static constexpr float LOG2E = 1.4426950408889634f;
static constexpr float LN2F  = 0.6931471805599453f;
static constexpr float S_E   = 6.0f;     // static log2 shift folded out of E
#define NEG_BIG (-1.0e38f)

__device__ __forceinline__ float fexp2(float x) { return __builtin_amdgcn_exp2f(x); }
__device__ __forceinline__ float flog2(float x) { return __builtin_amdgcn_logf(x); }
__device__ __forceinline__ f16x2 bcast_h2(f16x2 v, int src) {
    unsigned u = __builtin_amdgcn_readlane(__builtin_bit_cast(unsigned, v), src);
    return __builtin_bit_cast(f16x2, u);
}
__device__ __forceinline__ f16x2 pack_h2(float a, float b) {
    return __builtin_bit_cast(f16x2, __builtin_amdgcn_cvt_pkrtz(a, b));
}

// Full-wave (64-lane) fmax via DPP (VALU pipe) -> uniform value via lane 63.
__device__ __forceinline__ float wave_fmax_dpp(float x) {
#define DPP_STEP(ctrl)                                                        \
    do {                                                                      \
        int _s = __builtin_bit_cast(int, x);                                  \
        int _p = __builtin_amdgcn_update_dpp(_s, _s, (ctrl), 0xf, 0xf, false);\
        x = fmaxf(x, __builtin_bit_cast(float, _p));                          \
    } while (0)
    DPP_STEP(0x111);  // row_shr:1
    DPP_STEP(0x112);  // row_shr:2
    DPP_STEP(0x114);  // row_shr:4
    DPP_STEP(0x118);  // row_shr:8
    DPP_STEP(0x142);  // row_bcast:15
    DPP_STEP(0x143);  // row_bcast:31
#undef DPP_STEP
    return __builtin_bit_cast(float,
        __builtin_amdgcn_readlane(__builtin_bit_cast(int, x), 63));
}

// =====================================================================
// Kernel 1 (register-resident, column-sliced; global-best config, r14
// measured 106.5us total): 4 waves per (batch,chunk). M = C^T; wave w
// owns M columns [16w,16w+16) in regs (Bt[rb], 8 VGPRs). Step:
// acc[mb] = sum_kb A(mb,kb) x Bt[kb] (16 MFMAs, 4 indep depth-4
// chains), row-scale by cs*descale (f32, exact pow2), RNE f16 back to
// Bt. mfma_f32_16x16x16f16 D-layout == B-layout (HW-verified r8..r17).
// Session ledger (why this exact shape):
//  - (256,6) reg class: 4 waves/SIMD, VGPR 40, no spill. 8-wave class
//    spills (r11) or is grid-limited (r15); NCHT=32 grid helps chunk
//    ~1us but costs combine +4us (r16/r17). Dual-chain ILP null (r13).
//  - per-step: ballot-bitmap mask (SALU), SALU descale, delayed-2-step
//    renorm (exact pow2, D compensates), v_pk_max_f16 for the max.
//  - out zeroed in-kernel (memset node removed; r14 A/B: -0.8us).
// =====================================================================
template<int NCHT, int CHLT>
__global__ __launch_bounds__(256, 6)
void crf_chunk(const float* __restrict__ feats, const int* __restrict__ mask,
               const float* __restrict__ trans, f16_t* __restrict__ wsCt,
               float* __restrict__ wsD, float* __restrict__ out, int out_size) {
    const int c    = blockIdx.x;          // chunk
    const int b    = blockIdx.y;          // batch
    const int tid  = threadIdx.x;
    const int w    = tid >> 6;            // wave = column-slice owner
    const int lane = tid & 63;
    const int l15  = lane & 15;
    const int q    = lane >> 4;

    __shared__ float sF[CHLT][64];        // 2^(f_t*log2e) per step / M-row
    __shared__ f16_t Ml[64 * 72];         // epilogue transpose (16B-aligned rows)

    const int t0  = c * CHLT + 1;
    const int nst = (NS - t0 < CHLT) ? (NS - t0) : CHLT;

    // ---- A-const: E^T tiles. A(mb,kb) elem j = E[16kb+4q+j][16mb+l15]
    f16x4 Afrag[4][4];
    #pragma unroll
    for (int mb = 0; mb < 4; mb++)
        #pragma unroll
        for (int kb = 0; kb < 4; kb++) {
            f16x4 v;
            #pragma unroll
            for (int j = 0; j < 4; j++) {
                const int kk = 16 * kb + 4 * q + j;   // row of E
                const int mm = 16 * mb + l15;         // col of E
                float x = 0.f;
                if (kk < T && mm < T) x = fexp2(fmaf(trans[kk * T + mm], LOG2E, -S_E));
                v[j] = (f16_t)x;
            }
            Afrag[mb][kb] = v;
        }

    // ---- preload sF (exp2 once); 4 waves stripe the rows
    for (int r = w; r < CHLT; r += 4) {
        int tl = t0 + r; tl = tl < NS ? tl : NS - 1;
        float fv = (lane < T && r < nst) ? feats[((size_t)b * NS + tl) * T + lane] : 0.f;
        sF[r][lane] = (lane < T && r < nst) ? fexp2(fv * LOG2E) : 0.f;
    }

    // ---- mask bitmap (one ballot; per-step test is SALU)
    unsigned long long bm;
    {
        int tl = t0 + lane; tl = tl < NS ? tl : NS - 1;
        int mv = (lane < nst) ? mask[b * NS + tl] : 0;
        bm = __ballot(mv != 0);
    }
    __syncthreads();                      // sF visible to all waves

    // ---- init wave's slice of M = I: tile rb is I-block (rb, w)
    f16x4 Bt[4];
    #pragma unroll
    for (int rb = 0; rb < 4; rb++) {
        f16x4 v;
        #pragma unroll
        for (int j = 0; j < 4; j++)
            v[j] = (f16_t)((rb == w && 4 * q + j == l15) ? 1.f : 0.f);
        Bt[rb] = v;
    }

    float D  = 0.f;
    float m1 = 1.f, m2 = 1.f;             // wave max from s-1, s-2 (delayed renorm)

    for (int s = 0; s < nst; s++) {
        if ((bm >> s) & 1ull) {
            // descale from max TWO doit-steps back (exact pow2; D compensates)
            int ebits = (int)((__float_as_uint(m2) >> 23) & 255) - 127;
            ebits = ebits > 14 ? 14 : (ebits < -14 ? -14 : ebits);
            const float descale = __uint_as_float((unsigned)(127 - ebits) << 23);
            D += (float)ebits + S_E;

            // 16 MFMAs: 4 independent depth-4 accumulate chains
            const f32x4 zz = {0.f, 0.f, 0.f, 0.f};
            f32x4 acc[4];
            #pragma unroll
            for (int mb = 0; mb < 4; mb++)
                acc[mb] = __builtin_amdgcn_mfma_f32_16x16x16f16(Afrag[mb][0], Bt[0], zz, 0, 0, 0);
            #pragma unroll
            for (int kb = 1; kb < 4; kb++)
                #pragma unroll
                for (int mb = 0; mb < 4; mb++)
                    acc[mb] = __builtin_amdgcn_mfma_f32_16x16x16f16(Afrag[mb][kb], Bt[kb], acc[mb], 0, 0, 0);

            // per-mb: load cs, fold descale (exact pow2), scale, RNE f16;
            // wm via packed f16 max on the stored words (v_pk_max_f16)
            f16x2 wmax2 = {(f16_t)0.f, (f16_t)0.f};
            #pragma unroll
            for (int mb = 0; mb < 4; mb++) {
                f32x4 cs = *(const f32x4*)&sF[s][16 * mb + 4 * q];
                float v0 = acc[mb][0] * (cs[0] * descale);
                float v1 = acc[mb][1] * (cs[1] * descale);
                float v2 = acc[mb][2] * (cs[2] * descale);
                float v3 = acc[mb][3] * (cs[3] * descale);
                f16x4 hv;
                hv[0] = (f16_t)v0; hv[1] = (f16_t)v1;   // RNE, matches prior rounds
                hv[2] = (f16_t)v2; hv[3] = (f16_t)v3;
                Bt[mb] = hv;       // D-layout == B-layout: feeds next step directly
                f16x2 lo = __builtin_shufflevector(hv, hv, 0, 1);
                f16x2 hi = __builtin_shufflevector(hv, hv, 2, 3);
                wmax2 = __builtin_elementwise_max(wmax2,
                          __builtin_elementwise_max(lo, hi));
            }
            float wm = fmaxf((float)wmax2[0], (float)wmax2[1]);

            m2 = m1;
            m1 = wave_fmax_dpp(wm);        // consumed two steps later
        }
    }

    // ---- epilogue: waves dump tiles -> barrier -> coalesced store
    {
        const int P2 = 72;
        #pragma unroll
        for (int rb = 0; rb < 4; rb++) {
            f16x4 v = Bt[rb];
            #pragma unroll
            for (int r = 0; r < 4; r++)
                Ml[(16 * rb + 4 * q + r) * P2 + 16 * w + l15] = v[r];
        }
        __syncthreads();
        // wsCt row j = M row j = column j of C (combine lane j's layout)
        const int row = tid >> 2;          // 0..63
        const int seg = tid & 3;           // 32 B segment
        const f16_t* src = &Ml[row * P2 + seg * 16];
        f16_t* dst = wsCt + ((size_t)(b * NCHT + c)) * 4096 + row * 64 + seg * 16;
        ((int4*)dst)[0] = *(const int4*)&src[0];
        ((int4*)dst)[1] = *(const int4*)&src[8];
    }
    if (lane == 0) wsD[(b * NCHT + c) * 4 + w] = D;   // per-wave (per-16-C-rows) shift

    // ---- zero `out` (replaces the hipMemsetAsync graph node; visible to
    //      the later combine dispatch via same-stream ordering)
    if (c == 0 && b == 0 && tid < out_size) out[tid] = 0.f;
}

// =====================================================================
// Kernel 2 (r14-verified, best-measured): 2 waves per batch. Wave 0:
// part-chain over NCHT chunk matrices (lane j holds column j of C,
// 128 B contiguous, double-buffered bufA/bufB via unrolled lambda).
// Wave 1: gold score. Dq[lane>>4] absorbs the per-wave renorm.
// (2-deep/3-buffer variant measured identical - r15; LDS-streamed
// variant measured worse - r17.)
// =====================================================================
template<int NCHT>
__global__ __launch_bounds__(128, 1)
void crf_combine(const float* __restrict__ feats, const int* __restrict__ mask,
                 const int* __restrict__ tags, const float* __restrict__ trans,
                 const f16_t* __restrict__ wsCt, const float* __restrict__ wsD,
                 float* __restrict__ out) {
    const int b    = blockIdx.x;
    const int tid  = threadIdx.x;
    const int wv   = tid >> 6;
    const int lane = tid & 63;

    __shared__ float sGold;
    float fwd = 0.f;

    if (wv == 1) {
        float gsum = 0.f;
        int   lcnt = 0;
        for (int s = lane; s < NS; s += 64) {
            int   m  = mask[b * NS + s];
            int   tg = tags[b * NS + s];
            int   pv = (s == 0) ? START_TAG : tags[b * NS + s - 1];
            float e  = feats[((size_t)b * NS + s) * T + tg];
            float tr = trans[pv * T + tg];
            if (m) { gsum += e + tr; lcnt += 1; }
        }
        #pragma unroll
        for (int off = 32; off > 0; off >>= 1) {
            gsum += __shfl_down(gsum, off, 64);
            lcnt += __shfl_down(lcnt, off, 64);
        }
        if (lane == 0) sGold = gsum + trans[tags[b * NS + lcnt - 1] * T + STOP_TAG];
    } else {
        float part = (lane < T)
            ? (feats[(size_t)b * NS * T + lane] + trans[START_TAG * T + lane]) * LOG2E
            : NEG_BIG;

        float Dq[NCHT];
        #pragma unroll
        for (int cc = 0; cc < NCHT; cc++)
            Dq[cc] = wsD[(b * NCHT + cc) * 4 + (lane >> 4)];

        int bufA[32], bufB[32];
        {
            const f16_t* src = wsCt + (size_t)b * NCHT * 4096 + lane * 64;
            #pragma unroll
            for (int kk = 0; kk < 8; kk++)
                *(int4*)&bufA[4 * kk] = ((const int4*)src)[kk];
        }

        auto cbody = [&](int (&cur)[32], int (&nxt)[32], int cc) {
            if (cc + 1 < NCHT) {
                const f16_t* src = wsCt + (size_t)(b * NCHT + cc + 1) * 4096 + lane * 64;
                #pragma unroll
                for (int kk = 0; kk < 8; kk++)
                    *(int4*)&nxt[4 * kk] = ((const int4*)src)[kk];
            }

            float tmp = part + Dq[cc];
            float sft = wave_fmax_dpp(tmp);
            float ex  = fexp2(tmp - sft);
            float exo = __shfl_xor(ex, 1, 64);
            f16x2 pk  = pack_h2(ex, exo);

            float a0 = 0.f, a1 = 0.f, a2 = 0.f, a3 = 0.f;
            #pragma unroll
            for (int k = 0; k < 25; k += 4) {
                a0 = __builtin_amdgcn_fdot2(bcast_h2(pk, 2 * k), __builtin_bit_cast(f16x2, cur[k]), a0, false);
                if (k + 1 < 25) a1 = __builtin_amdgcn_fdot2(bcast_h2(pk, 2 * (k + 1)), __builtin_bit_cast(f16x2, cur[k + 1]), a1, false);
                if (k + 2 < 25) a2 = __builtin_amdgcn_fdot2(bcast_h2(pk, 2 * (k + 2)), __builtin_bit_cast(f16x2, cur[k + 2]), a2, false);
                if (k + 3 < 25) a3 = __builtin_amdgcn_fdot2(bcast_h2(pk, 2 * (k + 3)), __builtin_bit_cast(f16x2, cur[k + 3]), a3, false);
            }
            part = sft + flog2((a0 + a1) + (a2 + a3));
        };

        #pragma unroll
        for (int p = 0; p < NCHT / 2; p++) {
            cbody(bufA, bufB, 2 * p);
            cbody(bufB, bufA, 2 * p + 1);
        }

        float v = (lane < T) ? part + trans[lane * T + STOP_TAG] * LOG2E : NEG_BIG;
        float mx = wave_fmax_dpp(v);
        float ee = (lane < T) ? fexp2(v - mx) : 0.f;
        #pragma unroll
        for (int off = 32; off > 0; off >>= 1) ee += __shfl_xor(ee, off, 64);
        fwd = (mx + flog2(ee)) * LN2F;
    }

    __syncthreads();
    if (tid == 0) atomicAdd(out, fwd - sGold);
}

extern "C" void kernel_launch(void* const* d_in, const int* in_sizes, int n_in,
                              void* d_out, int out_size, void* d_ws, size_t ws_size,
                              hipStream_t stream) {
    const float* feats = (const float*)d_in[0];
    const int*   mask  = (const int*)d_in[1];
    const int*   tags  = (const int*)d_in[2];
    const float* trans = (const float*)d_in[3];
    float* out = (float*)d_out;

    // NO hipMemsetAsync: `out` is zeroed inside crf_chunk (block (0,0));
    // same-stream ordering guarantees visibility to crf_combine.

    const size_t matBytes16 = (size_t)NB * 16 * 4096 * sizeof(f16_t);
    const size_t need16     = matBytes16 + (size_t)NB * 16 * 4 * sizeof(float);

    if (ws_size >= need16) {
        // best-measured config: 16 chunks x 32 steps, 1024 blocks x 4 waves
        f16_t* wsCt = (f16_t*)d_ws;
        float* wsD  = (float*)((char*)d_ws + matBytes16);
        crf_chunk<16, 32><<<dim3(16, NB), 256, 0, stream>>>(feats, mask, trans, wsCt, wsD, out, out_size);
        crf_combine<16><<<NB, 128, 0, stream>>>(feats, mask, tags, trans, wsCt, wsD, out);
    } else {
        // fallback: 8 chunks x 64 steps (fits 4.2 MB)
        const size_t matBytes8 = (size_t)NB * 8 * 4096 * sizeof(f16_t);
        f16_t* wsCt = (f16_t*)d_ws;
        float* wsD  = (float*)((char*)d_ws + matBytes8);
        crf_chunk<8, 64><<<dim3(8, NB), 256, 0, stream>>>(feats, mask, trans, wsCt, wsD, out, out_size);
        crf_combine<8><<<NB, 128, 0, stream>>>(feats, mask, tags, trans, wsCt, wsD, out);
    }
}